// Round 1
// baseline (165.767 us; speedup 1.0000x reference)
//
#include <hip/hip_runtime.h>

#define B_   4
#define C_   256
#define CR_  64
#define H_   128
#define W_   128
#define HW_  (H_ * W_)
#define G_   16
#define GC_  16
#define KO_  144   // K*K*G = 9*16
#define EPS_ 1e-5f

// ---------------------------------------------------------------------------
// prep: w1t[c*64+o] = w1[o*256+c] * (gamma[o]*rsqrt(var[o]+eps));
//       bias2[o]    = beta[o] - mean[o]*alpha[o]
// ---------------------------------------------------------------------------
__global__ void prep_kernel(const float* __restrict__ w1,
                            const float* __restrict__ gamma,
                            const float* __restrict__ beta,
                            const float* __restrict__ mean,
                            const float* __restrict__ var,
                            float* __restrict__ w1t,
                            float* __restrict__ bias2) {
    int idx = blockIdx.x * blockDim.x + threadIdx.x;
    if (idx < C_ * CR_) {
        int o = idx & (CR_ - 1);
        int c = idx >> 6;
        float alpha = gamma[o] * rsqrtf(var[o] + EPS_);
        w1t[c * CR_ + o] = w1[o * C_ + c] * alpha;
        if (idx < CR_) {
            bias2[idx] = beta[idx] - mean[idx] * alpha;  // o == idx here
        }
    }
}

// ---------------------------------------------------------------------------
// conv1 + BN + ReLU: h1[b][o][hw] = relu(sum_c x[b][c][hw]*w1t[c][o] + bias2[o])
// thread = (o-half, pixel). half from blockIdx (uniform -> scalar weight loads)
// ---------------------------------------------------------------------------
__global__ __launch_bounds__(256) void conv1_kernel(const float* __restrict__ x,
                                                    const float* __restrict__ w1t,
                                                    const float* __restrict__ bias2,
                                                    float* __restrict__ h1) {
    const int half = blockIdx.x >> 8;                       // 0..1 (uniform)
    const int p    = ((blockIdx.x & 255) << 8) + threadIdx.x;  // 0..65535
    const int b    = p >> 14;
    const int hw   = p & (HW_ - 1);
    const int ob   = half * 32;

    const float* xp = x + (size_t)b * C_ * HW_ + hw;

    float acc[32];
#pragma unroll
    for (int j = 0; j < 32; ++j) acc[j] = 0.f;

    for (int c = 0; c < C_; ++c) {
        float xv = xp[(size_t)c * HW_];
        const float4* w = reinterpret_cast<const float4*>(w1t + c * CR_ + ob);
#pragma unroll
        for (int j = 0; j < 8; ++j) {
            float4 wv = w[j];
            acc[4 * j + 0] = fmaf(xv, wv.x, acc[4 * j + 0]);
            acc[4 * j + 1] = fmaf(xv, wv.y, acc[4 * j + 1]);
            acc[4 * j + 2] = fmaf(xv, wv.z, acc[4 * j + 2]);
            acc[4 * j + 3] = fmaf(xv, wv.w, acc[4 * j + 3]);
        }
    }

    float* hp = h1 + ((size_t)b * CR_ + ob) * HW_ + hw;
#pragma unroll
    for (int j = 0; j < 32; ++j) {
        float v = acc[j] + bias2[ob + j];
        hp[(size_t)j * HW_] = fmaxf(v, 0.f);
    }
}

// ---------------------------------------------------------------------------
// conv2: wk[b][o][hw] = sum_cc h1[b][cc][hw]*w2[o][cc] + b2[o]
// thread = (quarter q of 144 outputs, pixel); h1 row cached in 64 registers
// ---------------------------------------------------------------------------
__global__ __launch_bounds__(256) void conv2_kernel(const float* __restrict__ h1,
                                                    const float* __restrict__ w2,
                                                    const float* __restrict__ b2,
                                                    float* __restrict__ wk) {
    const int q  = blockIdx.x >> 8;                         // 0..3 (uniform)
    const int p  = ((blockIdx.x & 255) << 8) + threadIdx.x;
    const int b  = p >> 14;
    const int hw = p & (HW_ - 1);

    const float* hp = h1 + (size_t)b * CR_ * HW_ + hw;
    float h[CR_];
#pragma unroll
    for (int cc = 0; cc < CR_; ++cc) h[cc] = hp[(size_t)cc * HW_];

    float* wkp = wk + (size_t)b * KO_ * HW_ + hw;
    const int o0 = q * 36;
    for (int o = o0; o < o0 + 36; ++o) {
        const float4* w = reinterpret_cast<const float4*>(w2 + o * CR_);
        float a0 = b2[o], a1 = 0.f, a2 = 0.f, a3 = 0.f;
#pragma unroll
        for (int j = 0; j < 16; ++j) {
            float4 wv = w[j];
            a0 = fmaf(h[4 * j + 0], wv.x, a0);
            a1 = fmaf(h[4 * j + 1], wv.y, a1);
            a2 = fmaf(h[4 * j + 2], wv.z, a2);
            a3 = fmaf(h[4 * j + 3], wv.w, a3);
        }
        wkp[(size_t)o * HW_] = (a0 + a1) + (a2 + a3);
    }
}

// ---------------------------------------------------------------------------
// involution: out[b][g*16+cc][hw] = sum_k wk[b][g*9+k][hw] * x[b][g*16+cc][hw+off(k)]
// thread = (b, g, pixel); wk9 held in registers, reused over 16 channels
// ---------------------------------------------------------------------------
__global__ __launch_bounds__(256) void inv_kernel(const float* __restrict__ x,
                                                  const float* __restrict__ wk,
                                                  float* __restrict__ out) {
    const int tid = blockIdx.x * 256 + threadIdx.x;   // 0 .. B*G*HW-1
    const int hw  = tid & (HW_ - 1);
    const int g   = (tid >> 14) & (G_ - 1);
    const int b   = tid >> 18;
    const int h   = hw >> 7;
    const int w   = hw & (W_ - 1);

    float wk9[9];
    const float* wkp = wk + ((size_t)b * KO_ + g * 9) * HW_ + hw;
#pragma unroll
    for (int k = 0; k < 9; ++k) wk9[k] = wkp[(size_t)k * HW_];

    const float* xp = x + ((size_t)b * C_ + g * GC_) * HW_ + hw;
    float* op       = out + ((size_t)b * C_ + g * GC_) * HW_ + hw;

    const bool hok0 = (h > 0), hok2 = (h < H_ - 1);
    const bool wok0 = (w > 0), wok2 = (w < W_ - 1);

#pragma unroll 4
    for (int cc = 0; cc < GC_; ++cc) {
        const float* xc = xp + (size_t)cc * HW_;
        float acc = 0.f;
        if (hok0) {
            float xm = wok0 ? xc[-W_ - 1] : 0.f;
            float x0 = xc[-W_];
            float xq = wok2 ? xc[-W_ + 1] : 0.f;
            acc = fmaf(wk9[0], xm, acc);
            acc = fmaf(wk9[1], x0, acc);
            acc = fmaf(wk9[2], xq, acc);
        }
        {
            float xm = wok0 ? xc[-1] : 0.f;
            float x0 = xc[0];
            float xq = wok2 ? xc[1] : 0.f;
            acc = fmaf(wk9[3], xm, acc);
            acc = fmaf(wk9[4], x0, acc);
            acc = fmaf(wk9[5], xq, acc);
        }
        if (hok2) {
            float xm = wok0 ? xc[W_ - 1] : 0.f;
            float x0 = xc[W_];
            float xq = wok2 ? xc[W_ + 1] : 0.f;
            acc = fmaf(wk9[6], xm, acc);
            acc = fmaf(wk9[7], x0, acc);
            acc = fmaf(wk9[8], xq, acc);
        }
        op[(size_t)cc * HW_] = acc;
    }
}

// ---------------------------------------------------------------------------
extern "C" void kernel_launch(void* const* d_in, const int* in_sizes, int n_in,
                              void* d_out, int out_size, void* d_ws, size_t ws_size,
                              hipStream_t stream) {
    const float* x     = (const float*)d_in[0];
    const float* w1    = (const float*)d_in[1];
    const float* gamma = (const float*)d_in[2];
    const float* beta  = (const float*)d_in[3];
    const float* mean  = (const float*)d_in[4];
    const float* var   = (const float*)d_in[5];
    const float* w2    = (const float*)d_in[6];
    const float* b2    = (const float*)d_in[7];
    float* out = (float*)d_out;

    char* ws = (char*)d_ws;
    float* w1t   = (float*)(ws);                  // 64 KB
    float* bias2 = (float*)(ws + (64 << 10));     // 256 B
    float* h1    = (float*)(ws + (1 << 20));      // 16.78 MB  [B][64][HW]
    float* wk    = (float*)(ws + (18 << 20));     // 36 MB     [B][144][HW]

    hipLaunchKernelGGL(prep_kernel, dim3(64), dim3(256), 0, stream,
                       w1, gamma, beta, mean, var, w1t, bias2);
    hipLaunchKernelGGL(conv1_kernel, dim3(512), dim3(256), 0, stream,
                       x, w1t, bias2, h1);
    hipLaunchKernelGGL(conv2_kernel, dim3(1024), dim3(256), 0, stream,
                       h1, w2, b2, wk);
    hipLaunchKernelGGL(inv_kernel, dim3(4096), dim3(256), 0, stream,
                       x, wk, out);
}

// Round 2
// 145.977 us; speedup vs baseline: 1.1356x; 1.1356x over previous
//
#include <hip/hip_runtime.h>

#define B_   4
#define C_   256
#define CR_  64
#define H_   128
#define W_   128
#define HW_  (H_ * W_)
#define G_   16
#define GC_  16
#define KO_  144   // K*K*G = 9*16
#define EPS_ 1e-5f

// ---------------------------------------------------------------------------
// prep: w1t[c*64+o] = w1[o*256+c] * (gamma[o]*rsqrt(var[o]+eps));
//       bias2[o]    = beta[o] - mean[o]*alpha[o]
// ---------------------------------------------------------------------------
__global__ void prep_kernel(const float* __restrict__ w1,
                            const float* __restrict__ gamma,
                            const float* __restrict__ beta,
                            const float* __restrict__ mean,
                            const float* __restrict__ var,
                            float* __restrict__ w1t,
                            float* __restrict__ bias2) {
    int idx = blockIdx.x * blockDim.x + threadIdx.x;
    if (idx < C_ * CR_) {
        int o = idx & (CR_ - 1);
        int c = idx >> 6;
        float alpha = gamma[o] * rsqrtf(var[o] + EPS_);
        w1t[c * CR_ + o] = w1[o * C_ + c] * alpha;
        if (idx < CR_) {
            bias2[idx] = beta[idx] - mean[idx] * alpha;  // o == idx here
        }
    }
}

// ---------------------------------------------------------------------------
// conv1 + BN + ReLU: h1[b][o][hw] = relu(sum_c x[b][c][hw]*w1t[c][o] + bias2[o])
// thread = (o-quarter, pixel). Weights for the quarter staged in LDS
// (uniform-address broadcast reads). x loads software-pipelined 8 deep.
// grid = 1024 blocks -> 4 waves/SIMD.
// ---------------------------------------------------------------------------
__global__ __launch_bounds__(256) void conv1_kernel(const float* __restrict__ x,
                                                    const float* __restrict__ w1t,
                                                    const float* __restrict__ bias2,
                                                    float* __restrict__ h1) {
    __shared__ float wlds[C_][16];                       // 16 KB
    const int q  = blockIdx.x >> 8;                      // 0..3 (uniform)
    const int p  = ((blockIdx.x & 255) << 8) + threadIdx.x;
    const int b  = p >> 14;
    const int hw = p & (HW_ - 1);
    const int ob = q * 16;

    for (int i = threadIdx.x; i < C_ * 16; i += 256) {
        int c = i >> 4, j = i & 15;
        wlds[c][j] = w1t[c * CR_ + ob + j];
    }
    __syncthreads();

    const float* xp = x + (size_t)b * C_ * HW_ + hw;

    float acc[16];
#pragma unroll
    for (int j = 0; j < 16; ++j) acc[j] = 0.f;

    float xv[8], xn[8];
#pragma unroll
    for (int u = 0; u < 8; ++u) xv[u] = xp[(size_t)u * HW_];

    for (int c0 = 0; c0 < C_ - 8; c0 += 8) {
        // prefetch next chunk (8 independent loads in flight)
#pragma unroll
        for (int u = 0; u < 8; ++u) xn[u] = xp[(size_t)(c0 + 8 + u) * HW_];
#pragma unroll
        for (int u = 0; u < 8; ++u) {
            const float4* w = reinterpret_cast<const float4*>(&wlds[c0 + u][0]);
            float xs = xv[u];
#pragma unroll
            for (int j = 0; j < 4; ++j) {
                float4 wv = w[j];
                acc[4 * j + 0] = fmaf(xs, wv.x, acc[4 * j + 0]);
                acc[4 * j + 1] = fmaf(xs, wv.y, acc[4 * j + 1]);
                acc[4 * j + 2] = fmaf(xs, wv.z, acc[4 * j + 2]);
                acc[4 * j + 3] = fmaf(xs, wv.w, acc[4 * j + 3]);
            }
        }
#pragma unroll
        for (int u = 0; u < 8; ++u) xv[u] = xn[u];
    }
    // epilogue chunk (c = C_-8 .. C_-1)
#pragma unroll
    for (int u = 0; u < 8; ++u) {
        const float4* w = reinterpret_cast<const float4*>(&wlds[C_ - 8 + u][0]);
        float xs = xv[u];
#pragma unroll
        for (int j = 0; j < 4; ++j) {
            float4 wv = w[j];
            acc[4 * j + 0] = fmaf(xs, wv.x, acc[4 * j + 0]);
            acc[4 * j + 1] = fmaf(xs, wv.y, acc[4 * j + 1]);
            acc[4 * j + 2] = fmaf(xs, wv.z, acc[4 * j + 2]);
            acc[4 * j + 3] = fmaf(xs, wv.w, acc[4 * j + 3]);
        }
    }

    float* hp = h1 + ((size_t)b * CR_ + ob) * HW_ + hw;
#pragma unroll
    for (int j = 0; j < 16; ++j) {
        float v = acc[j] + bias2[ob + j];
        hp[(size_t)j * HW_] = fmaxf(v, 0.f);
    }
}

// ---------------------------------------------------------------------------
// conv2: wk[b][o][hw] = sum_cc h1[b][cc][hw]*w2[o][cc] + b2[o]
// thread = (o-quarter, pixel); h1 row in 64 registers, weight quarter (9 KB)
// staged in LDS, broadcast reads. o-loop unrolled x2 for DS/VALU overlap.
// ---------------------------------------------------------------------------
__global__ __launch_bounds__(256) void conv2_kernel(const float* __restrict__ h1,
                                                    const float* __restrict__ w2,
                                                    const float* __restrict__ b2,
                                                    float* __restrict__ wk) {
    __shared__ float wlds[36][64];                       // 9 KB
    __shared__ float blds[36];
    const int q  = blockIdx.x >> 8;                      // 0..3 (uniform)
    const int p  = ((blockIdx.x & 255) << 8) + threadIdx.x;
    const int b  = p >> 14;
    const int hw = p & (HW_ - 1);
    const int o0 = q * 36;

    for (int i = threadIdx.x; i < 36 * 64; i += 256) {
        int o = i >> 6, j = i & 63;
        wlds[o][j] = w2[(o0 + o) * CR_ + j];
    }
    if (threadIdx.x < 36) blds[threadIdx.x] = b2[o0 + threadIdx.x];
    __syncthreads();

    const float* hp = h1 + (size_t)b * CR_ * HW_ + hw;
    float h[CR_];
#pragma unroll
    for (int cc = 0; cc < CR_; ++cc) h[cc] = hp[(size_t)cc * HW_];

    float* wkp = wk + ((size_t)b * KO_ + o0) * HW_ + hw;
#pragma unroll 2
    for (int o = 0; o < 36; ++o) {
        const float4* w = reinterpret_cast<const float4*>(&wlds[o][0]);
        float a0 = blds[o], a1 = 0.f, a2 = 0.f, a3 = 0.f;
#pragma unroll
        for (int j = 0; j < 16; ++j) {
            float4 wv = w[j];
            a0 = fmaf(h[4 * j + 0], wv.x, a0);
            a1 = fmaf(h[4 * j + 1], wv.y, a1);
            a2 = fmaf(h[4 * j + 2], wv.z, a2);
            a3 = fmaf(h[4 * j + 3], wv.w, a3);
        }
        wkp[(size_t)o * HW_] = (a0 + a1) + (a2 + a3);
    }
}

// ---------------------------------------------------------------------------
// involution: out[b][g*16+cc][hw] = sum_k wk[b][g*9+k][hw] * x[b][g*16+cc][hw+off(k)]
// thread = (b, g, pixel); wk9 held in registers, reused over 16 channels
// ---------------------------------------------------------------------------
__global__ __launch_bounds__(256) void inv_kernel(const float* __restrict__ x,
                                                  const float* __restrict__ wk,
                                                  float* __restrict__ out) {
    const int tid = blockIdx.x * 256 + threadIdx.x;   // 0 .. B*G*HW-1
    const int hw  = tid & (HW_ - 1);
    const int g   = (tid >> 14) & (G_ - 1);
    const int b   = tid >> 18;
    const int h   = hw >> 7;
    const int w   = hw & (W_ - 1);

    float wk9[9];
    const float* wkp = wk + ((size_t)b * KO_ + g * 9) * HW_ + hw;
#pragma unroll
    for (int k = 0; k < 9; ++k) wk9[k] = wkp[(size_t)k * HW_];

    const float* xp = x + ((size_t)b * C_ + g * GC_) * HW_ + hw;
    float* op       = out + ((size_t)b * C_ + g * GC_) * HW_ + hw;

    const bool hok0 = (h > 0), hok2 = (h < H_ - 1);
    const bool wok0 = (w > 0), wok2 = (w < W_ - 1);

#pragma unroll 4
    for (int cc = 0; cc < GC_; ++cc) {
        const float* xc = xp + (size_t)cc * HW_;
        float acc = 0.f;
        if (hok0) {
            float xm = wok0 ? xc[-W_ - 1] : 0.f;
            float x0 = xc[-W_];
            float xq = wok2 ? xc[-W_ + 1] : 0.f;
            acc = fmaf(wk9[0], xm, acc);
            acc = fmaf(wk9[1], x0, acc);
            acc = fmaf(wk9[2], xq, acc);
        }
        {
            float xm = wok0 ? xc[-1] : 0.f;
            float x0 = xc[0];
            float xq = wok2 ? xc[1] : 0.f;
            acc = fmaf(wk9[3], xm, acc);
            acc = fmaf(wk9[4], x0, acc);
            acc = fmaf(wk9[5], xq, acc);
        }
        if (hok2) {
            float xm = wok0 ? xc[W_ - 1] : 0.f;
            float x0 = xc[W_];
            float xq = wok2 ? xc[W_ + 1] : 0.f;
            acc = fmaf(wk9[6], xm, acc);
            acc = fmaf(wk9[7], x0, acc);
            acc = fmaf(wk9[8], xq, acc);
        }
        op[(size_t)cc * HW_] = acc;
    }
}

// ---------------------------------------------------------------------------
extern "C" void kernel_launch(void* const* d_in, const int* in_sizes, int n_in,
                              void* d_out, int out_size, void* d_ws, size_t ws_size,
                              hipStream_t stream) {
    const float* x     = (const float*)d_in[0];
    const float* w1    = (const float*)d_in[1];
    const float* gamma = (const float*)d_in[2];
    const float* beta  = (const float*)d_in[3];
    const float* mean  = (const float*)d_in[4];
    const float* var   = (const float*)d_in[5];
    const float* w2    = (const float*)d_in[6];
    const float* b2    = (const float*)d_in[7];
    float* out = (float*)d_out;

    char* ws = (char*)d_ws;
    float* w1t   = (float*)(ws);                  // 64 KB
    float* bias2 = (float*)(ws + (64 << 10));     // 256 B
    float* h1    = (float*)(ws + (1 << 20));      // 16.78 MB  [B][64][HW]
    float* wk    = (float*)(ws + (18 << 20));     // 36 MB     [B][144][HW]

    hipLaunchKernelGGL(prep_kernel, dim3(64), dim3(256), 0, stream,
                       w1, gamma, beta, mean, var, w1t, bias2);
    hipLaunchKernelGGL(conv1_kernel, dim3(1024), dim3(256), 0, stream,
                       x, w1t, bias2, h1);
    hipLaunchKernelGGL(conv2_kernel, dim3(1024), dim3(256), 0, stream,
                       h1, w2, b2, wk);
    hipLaunchKernelGGL(inv_kernel, dim3(4096), dim3(256), 0, stream,
                       x, wk, out);
}

// Round 3
// 141.968 us; speedup vs baseline: 1.1676x; 1.0282x over previous
//
#include <hip/hip_runtime.h>

#define B_   4
#define C_   256
#define CR_  64
#define H_   128
#define W_   128
#define HW_  (H_ * W_)
#define G_   16
#define GC_  16
#define KO_  144   // K*K*G = 9*16
#define EPS_ 1e-5f

// ---------------------------------------------------------------------------
// prep: w1t[c*64+o] = w1[o*256+c]*alpha[o],  alpha = gamma*rsqrt(var+eps)
//       bias2[o]    = beta[o] - mean[o]*alpha[o]
//       w2t[k*192 + g*12 + j] = w2[(g*9+j)*64 + k]  (j<9; pad j=9..11 with 0)
// ---------------------------------------------------------------------------
__global__ void prep_kernel(const float* __restrict__ w1,
                            const float* __restrict__ gamma,
                            const float* __restrict__ beta,
                            const float* __restrict__ mean,
                            const float* __restrict__ var,
                            const float* __restrict__ w2,
                            float* __restrict__ w1t,
                            float* __restrict__ bias2,
                            float* __restrict__ w2t) {
    int idx = blockIdx.x * 256 + threadIdx.x;          // 0..16383
    if (idx < C_ * CR_) {
        int o = idx & 63, c = idx >> 6;
        float alpha = gamma[o] * rsqrtf(var[o] + EPS_);
        w1t[c * CR_ + o] = w1[o * C_ + c] * alpha;
        if (idx < CR_) bias2[idx] = beta[idx] - mean[idx] * alpha;
    }
    if (idx < CR_ * 192) {
        int k = idx / 192, r = idx % 192;
        int g = r / 12, j = r % 12;
        w2t[idx] = (j < 9) ? w2[(g * 9 + j) * CR_ + k] : 0.f;
    }
}

// ---------------------------------------------------------------------------
// fused conv1(+BN+ReLU) + conv2. One block = 128-pixel tile.
// Phase 1: h[64][128] = relu(W1(64x256) * x(256x128) + bias)   (h stays in LDS)
// Phase 2: wk[144][128] = W2(144x64) * h(64x128) + b2
// Thread (og=tid>>4, pg=tid&15):
//   phase1: outputs og*4+{0..3},  pixels pg*4+{0..3} and 64+pg*4+{0..3}
//   phase2: outputs og*9+{0..8},  same pixel split
// ---------------------------------------------------------------------------
__global__ __launch_bounds__(256) void conv12_kernel(
        const float* __restrict__ x,
        const float* __restrict__ w1t,
        const float* __restrict__ bias2,
        const float* __restrict__ w2t,
        const float* __restrict__ b2,
        float* __restrict__ wk) {
    __shared__ float hbuf[CR_ * 128];    // 32 KB, persists phase1 -> phase2
    __shared__ float pbuf[6144];         // 24 KB scratch (xs+ws1 | ws2)

    const int tid = threadIdx.x;
    const int og  = tid >> 4;            // 0..15
    const int pg  = tid & 15;            // 0..15
    const int px0 = blockIdx.x * 128;
    const int b   = px0 >> 14;
    const int hw0 = px0 & (HW_ - 1);

    const float* xb = x + (size_t)b * C_ * HW_ + hw0;

    // ======================= phase 1: conv1 ============================
    float acc1[4][8];
#pragma unroll
    for (int m = 0; m < 4; ++m)
#pragma unroll
        for (int n = 0; n < 8; ++n) acc1[m][n] = 0.f;

    float* xs  = pbuf;                   // [32][128]
    float* ws1 = pbuf + 4096;            // [32][64]

    for (int kc = 0; kc < 8; ++kc) {
        const int c0 = kc * 32;
        for (int i = tid; i < 1024; i += 256) {       // x chunk: 16 KB
            int cc = i >> 5, seg = i & 31;
            *(float4*)&xs[cc * 128 + seg * 4] =
                *(const float4*)&xb[(size_t)(c0 + cc) * HW_ + seg * 4];
        }
        for (int i = tid; i < 512; i += 256) {        // w1 chunk: 8 KB
            int cc = i >> 4, seg = i & 15;
            *(float4*)&ws1[cc * 64 + seg * 4] =
                *(const float4*)&w1t[(c0 + cc) * CR_ + seg * 4];
        }
        __syncthreads();
#pragma unroll
        for (int k = 0; k < 32; ++k) {
            float4 wv = *(const float4*)&ws1[k * 64 + og * 4];
            float4 xa = *(const float4*)&xs[k * 128 + pg * 4];
            float4 xc = *(const float4*)&xs[k * 128 + 64 + pg * 4];
            float wm[4] = {wv.x, wv.y, wv.z, wv.w};
            float xn[8] = {xa.x, xa.y, xa.z, xa.w, xc.x, xc.y, xc.z, xc.w};
#pragma unroll
            for (int m = 0; m < 4; ++m)
#pragma unroll
                for (int n = 0; n < 8; ++n)
                    acc1[m][n] = fmaf(wm[m], xn[n], acc1[m][n]);
        }
        __syncthreads();
    }

    // bias + relu -> h tile in LDS
    {
        float bv[4];
#pragma unroll
        for (int m = 0; m < 4; ++m) bv[m] = bias2[og * 4 + m];
#pragma unroll
        for (int m = 0; m < 4; ++m) {
            int o = og * 4 + m;
            float4 v0, v1;
            v0.x = fmaxf(acc1[m][0] + bv[m], 0.f);
            v0.y = fmaxf(acc1[m][1] + bv[m], 0.f);
            v0.z = fmaxf(acc1[m][2] + bv[m], 0.f);
            v0.w = fmaxf(acc1[m][3] + bv[m], 0.f);
            v1.x = fmaxf(acc1[m][4] + bv[m], 0.f);
            v1.y = fmaxf(acc1[m][5] + bv[m], 0.f);
            v1.z = fmaxf(acc1[m][6] + bv[m], 0.f);
            v1.w = fmaxf(acc1[m][7] + bv[m], 0.f);
            *(float4*)&hbuf[o * 128 + pg * 4]      = v0;
            *(float4*)&hbuf[o * 128 + 64 + pg * 4] = v1;
        }
    }

    // ======================= phase 2: conv2 ============================
    float acc2[9][8];
#pragma unroll
    for (int m = 0; m < 9; ++m)
#pragma unroll
        for (int n = 0; n < 8; ++n) acc2[m][n] = 0.f;

    float b2v[9];
#pragma unroll
    for (int m = 0; m < 9; ++m) b2v[m] = b2[og * 9 + m];

    __syncthreads();   // h visible; xs/ws1 reads all done

    for (int kc = 0; kc < 2; ++kc) {
        const int k0 = kc * 32;
        // stage 32 rows of w2t (rows are contiguous: flat 24 KB copy)
        for (int i = tid; i < 1536; i += 256) {
            *(float4*)&pbuf[i * 4] =
                *(const float4*)&w2t[k0 * 192 + i * 4];
        }
        __syncthreads();
#pragma unroll
        for (int kk = 0; kk < 32; ++kk) {
            const float* wrow = &pbuf[kk * 192 + og * 12];
            float4 wv0 = *(const float4*)&wrow[0];
            float4 wv1 = *(const float4*)&wrow[4];
            float4 wv2 = *(const float4*)&wrow[8];
            float4 ha  = *(const float4*)&hbuf[(k0 + kk) * 128 + pg * 4];
            float4 hb  = *(const float4*)&hbuf[(k0 + kk) * 128 + 64 + pg * 4];
            float wm[9] = {wv0.x, wv0.y, wv0.z, wv0.w,
                           wv1.x, wv1.y, wv1.z, wv1.w, wv2.x};
            float hn[8] = {ha.x, ha.y, ha.z, ha.w, hb.x, hb.y, hb.z, hb.w};
#pragma unroll
            for (int m = 0; m < 9; ++m)
#pragma unroll
                for (int n = 0; n < 8; ++n)
                    acc2[m][n] = fmaf(wm[m], hn[n], acc2[m][n]);
        }
        __syncthreads();
    }

    // store wk tile
    float* wkp = wk + (size_t)b * KO_ * HW_ + hw0;
#pragma unroll
    for (int m = 0; m < 9; ++m) {
        int o = og * 9 + m;
        float4 v0, v1;
        v0.x = acc2[m][0] + b2v[m];
        v0.y = acc2[m][1] + b2v[m];
        v0.z = acc2[m][2] + b2v[m];
        v0.w = acc2[m][3] + b2v[m];
        v1.x = acc2[m][4] + b2v[m];
        v1.y = acc2[m][5] + b2v[m];
        v1.z = acc2[m][6] + b2v[m];
        v1.w = acc2[m][7] + b2v[m];
        *(float4*)&wkp[(size_t)o * HW_ + pg * 4]      = v0;
        *(float4*)&wkp[(size_t)o * HW_ + 64 + pg * 4] = v1;
    }
}

// ---------------------------------------------------------------------------
// involution: out[b][g*16+cc][hw] = sum_k wk[b][g*9+k][hw] * x[b][g*16+cc][hw+off(k)]
// thread = (b, g, pixel); wk9 held in registers, reused over 16 channels
// ---------------------------------------------------------------------------
__global__ __launch_bounds__(256) void inv_kernel(const float* __restrict__ x,
                                                  const float* __restrict__ wk,
                                                  float* __restrict__ out) {
    const int tid = blockIdx.x * 256 + threadIdx.x;   // 0 .. B*G*HW-1
    const int hw  = tid & (HW_ - 1);
    const int g   = (tid >> 14) & (G_ - 1);
    const int b   = tid >> 18;
    const int h   = hw >> 7;
    const int w   = hw & (W_ - 1);

    float wk9[9];
    const float* wkp = wk + ((size_t)b * KO_ + g * 9) * HW_ + hw;
#pragma unroll
    for (int k = 0; k < 9; ++k) wk9[k] = wkp[(size_t)k * HW_];

    const float* xp = x + ((size_t)b * C_ + g * GC_) * HW_ + hw;
    float* op       = out + ((size_t)b * C_ + g * GC_) * HW_ + hw;

    const bool hok0 = (h > 0), hok2 = (h < H_ - 1);
    const bool wok0 = (w > 0), wok2 = (w < W_ - 1);

#pragma unroll 4
    for (int cc = 0; cc < GC_; ++cc) {
        const float* xc = xp + (size_t)cc * HW_;
        float acc = 0.f;
        if (hok0) {
            float xm = wok0 ? xc[-W_ - 1] : 0.f;
            float x0 = xc[-W_];
            float xq = wok2 ? xc[-W_ + 1] : 0.f;
            acc = fmaf(wk9[0], xm, acc);
            acc = fmaf(wk9[1], x0, acc);
            acc = fmaf(wk9[2], xq, acc);
        }
        {
            float xm = wok0 ? xc[-1] : 0.f;
            float x0 = xc[0];
            float xq = wok2 ? xc[1] : 0.f;
            acc = fmaf(wk9[3], xm, acc);
            acc = fmaf(wk9[4], x0, acc);
            acc = fmaf(wk9[5], xq, acc);
        }
        if (hok2) {
            float xm = wok0 ? xc[W_ - 1] : 0.f;
            float x0 = xc[W_];
            float xq = wok2 ? xc[W_ + 1] : 0.f;
            acc = fmaf(wk9[6], xm, acc);
            acc = fmaf(wk9[7], x0, acc);
            acc = fmaf(wk9[8], xq, acc);
        }
        op[(size_t)cc * HW_] = acc;
    }
}

// ---------------------------------------------------------------------------
extern "C" void kernel_launch(void* const* d_in, const int* in_sizes, int n_in,
                              void* d_out, int out_size, void* d_ws, size_t ws_size,
                              hipStream_t stream) {
    const float* x     = (const float*)d_in[0];
    const float* w1    = (const float*)d_in[1];
    const float* gamma = (const float*)d_in[2];
    const float* beta  = (const float*)d_in[3];
    const float* mean  = (const float*)d_in[4];
    const float* var   = (const float*)d_in[5];
    const float* w2    = (const float*)d_in[6];
    const float* b2    = (const float*)d_in[7];
    float* out = (float*)d_out;

    char* ws = (char*)d_ws;
    float* w1t   = (float*)(ws);                  // 64 KB  [256][64]
    float* bias2 = (float*)(ws + (64 << 10));     // 256 B
    float* w2t   = (float*)(ws + (128 << 10));    // 48 KB  [64][192]
    float* wkbuf = (float*)(ws + (1 << 20));      // 36 MB  [B][144][HW]

    hipLaunchKernelGGL(prep_kernel, dim3(64), dim3(256), 0, stream,
                       w1, gamma, beta, mean, var, w2, w1t, bias2, w2t);
    hipLaunchKernelGGL(conv12_kernel, dim3(512), dim3(256), 0, stream,
                       x, w1t, bias2, w2t, b2, wkbuf);
    hipLaunchKernelGGL(inv_kernel, dim3(4096), dim3(256), 0, stream,
                       x, wkbuf, out);
}

// Round 4
// 117.070 us; speedup vs baseline: 1.4160x; 1.2127x over previous
//
#include <hip/hip_runtime.h>

#define B_   4
#define C_   256
#define CR_  64
#define H_   128
#define W_   128
#define HW_  (H_ * W_)
#define G_   16
#define GC_  16
#define KO_  144   // K*K*G = 9*16
#define EPS_ 1e-5f

// ---------------------------------------------------------------------------
// prep: w1t[c*64+o] = w1[o*256+c]*alpha[o],  alpha = gamma*rsqrt(var+eps)
//       bias2[o]    = beta[o] - mean[o]*alpha[o]
//       w2t[k*192 + g*12 + j] = w2[(g*9+j)*64 + k]  (j<9; pad j=9..11 with 0)
// ---------------------------------------------------------------------------
__global__ void prep_kernel(const float* __restrict__ w1,
                            const float* __restrict__ gamma,
                            const float* __restrict__ beta,
                            const float* __restrict__ mean,
                            const float* __restrict__ var,
                            const float* __restrict__ w2,
                            float* __restrict__ w1t,
                            float* __restrict__ bias2,
                            float* __restrict__ w2t) {
    int idx = blockIdx.x * 256 + threadIdx.x;          // 0..16383
    if (idx < C_ * CR_) {
        int o = idx & 63, c = idx >> 6;
        float alpha = gamma[o] * rsqrtf(var[o] + EPS_);
        w1t[c * CR_ + o] = w1[o * C_ + c] * alpha;
        if (idx < CR_) bias2[idx] = beta[idx] - mean[idx] * alpha;
    }
    if (idx < CR_ * 192) {
        int k = idx / 192, r = idx % 192;
        int g = r / 12, j = r % 12;
        w2t[idx] = (j < 9) ? w2[(g * 9 + j) * CR_ + k] : 0.f;
    }
}

// ---------------------------------------------------------------------------
// fused conv1(+BN+ReLU) + conv2. One block = 64-pixel tile, grid = 1024.
// LDS 34 KB -> 4 blocks/CU (16 waves/CU).
// Phase 1: h[64][64] = relu(W1(64x256) * x(256x64) + bias)   (h stays in LDS)
// Phase 2: wk[144][64] = W2(144x64) * h(64x64) + b2
// Thread (og=tid>>4, pg=tid&15):
//   phase1: outputs og*4+{0..3},  pixels pg*4+{0..3}   acc 4x4
//   phase2: outputs og*9+{0..8},  pixels pg*4+{0..3}   acc 9x4
// All LDS rows padded +4 floats (stride 68 / 196) -> conflict-free b128 ops.
// ---------------------------------------------------------------------------
#define XS_LD  68
#define HB_LD  68
#define W2_LD  196

__global__ __launch_bounds__(256) void conv12_kernel(
        const float* __restrict__ x,
        const float* __restrict__ w1t,
        const float* __restrict__ bias2,
        const float* __restrict__ w2t,
        const float* __restrict__ b2,
        float* __restrict__ wk) {
    __shared__ float hbuf[CR_ * HB_LD];          // 17 KB, persists p1 -> p2
    __shared__ float pbuf[2 * 32 * XS_LD];       // 17 KB scratch (xs+ws1 | ws2)

    const int tid = threadIdx.x;
    const int og  = tid >> 4;            // 0..15
    const int pg  = tid & 15;            // 0..15
    const int px0 = blockIdx.x * 64;
    const int b   = px0 >> 14;
    const int hw0 = px0 & (HW_ - 1);

    const float* xb = x + (size_t)b * C_ * HW_ + hw0;

    float* xs  = pbuf;                   // [32][XS_LD]
    float* ws1 = pbuf + 32 * XS_LD;      // [32][XS_LD]

    // ======================= phase 1: conv1 ============================
    float acc1[4][4];
#pragma unroll
    for (int m = 0; m < 4; ++m)
#pragma unroll
        for (int n = 0; n < 4; ++n) acc1[m][n] = 0.f;

    for (int kc = 0; kc < 8; ++kc) {
        const int c0 = kc * 32;
        {   // stage x chunk (32 ch x 64 px) + w1 chunk (32 ch x 64 out)
            int cc = tid >> 4, seg = tid & 15;             // 512 f4 jobs, 2/thread
            *(float4*)&xs[cc * XS_LD + seg * 4] =
                *(const float4*)&xb[(size_t)(c0 + cc) * HW_ + seg * 4];
            *(float4*)&xs[(cc + 16) * XS_LD + seg * 4] =
                *(const float4*)&xb[(size_t)(c0 + cc + 16) * HW_ + seg * 4];
            *(float4*)&ws1[cc * XS_LD + seg * 4] =
                *(const float4*)&w1t[(c0 + cc) * CR_ + seg * 4];
            *(float4*)&ws1[(cc + 16) * XS_LD + seg * 4] =
                *(const float4*)&w1t[(c0 + cc + 16) * CR_ + seg * 4];
        }
        __syncthreads();
#pragma unroll
        for (int k = 0; k < 32; ++k) {
            float4 wv = *(const float4*)&ws1[k * XS_LD + og * 4];
            float4 xa = *(const float4*)&xs[k * XS_LD + pg * 4];
            float wm[4] = {wv.x, wv.y, wv.z, wv.w};
            float xn[4] = {xa.x, xa.y, xa.z, xa.w};
#pragma unroll
            for (int m = 0; m < 4; ++m)
#pragma unroll
                for (int n = 0; n < 4; ++n)
                    acc1[m][n] = fmaf(wm[m], xn[n], acc1[m][n]);
        }
        __syncthreads();
    }

    // bias + relu -> h tile in LDS (no sync needed before: pbuf untouched)
    {
#pragma unroll
        for (int m = 0; m < 4; ++m) {
            int o = og * 4 + m;
            float bv = bias2[o];
            float4 v;
            v.x = fmaxf(acc1[m][0] + bv, 0.f);
            v.y = fmaxf(acc1[m][1] + bv, 0.f);
            v.z = fmaxf(acc1[m][2] + bv, 0.f);
            v.w = fmaxf(acc1[m][3] + bv, 0.f);
            *(float4*)&hbuf[o * HB_LD + pg * 4] = v;
        }
    }

    // ======================= phase 2: conv2 ============================
    float acc2[9][4];
#pragma unroll
    for (int m = 0; m < 9; ++m)
#pragma unroll
        for (int n = 0; n < 4; ++n) acc2[m][n] = 0.f;

    for (int kc = 0; kc < 4; ++kc) {
        const int k0 = kc * 16;
        // stage 16 rows of w2t into pbuf[16][W2_LD] (48 f4 per row)
        for (int i = tid; i < 768; i += 256) {
            int r = i / 48, c4 = i % 48;
            *(float4*)&pbuf[r * W2_LD + c4 * 4] =
                *(const float4*)&w2t[(k0 + r) * 192 + c4 * 4];
        }
        __syncthreads();   // also orders hbuf writes before hbuf reads (kc=0)
#pragma unroll
        for (int kk = 0; kk < 16; ++kk) {
            const float* wrow = &pbuf[kk * W2_LD + og * 12];
            float4 wv0 = *(const float4*)&wrow[0];
            float4 wv1 = *(const float4*)&wrow[4];
            float  wv2 = wrow[8];
            float4 ha  = *(const float4*)&hbuf[(k0 + kk) * HB_LD + pg * 4];
            float wm[9] = {wv0.x, wv0.y, wv0.z, wv0.w,
                           wv1.x, wv1.y, wv1.z, wv1.w, wv2};
            float hn[4] = {ha.x, ha.y, ha.z, ha.w};
#pragma unroll
            for (int m = 0; m < 9; ++m)
#pragma unroll
                for (int n = 0; n < 4; ++n)
                    acc2[m][n] = fmaf(wm[m], hn[n], acc2[m][n]);
        }
        __syncthreads();
    }

    // store wk tile
    float* wkp = wk + (size_t)b * KO_ * HW_ + hw0;
#pragma unroll
    for (int m = 0; m < 9; ++m) {
        int o = og * 9 + m;
        float bv = b2[o];
        float4 v;
        v.x = acc2[m][0] + bv;
        v.y = acc2[m][1] + bv;
        v.z = acc2[m][2] + bv;
        v.w = acc2[m][3] + bv;
        *(float4*)&wkp[(size_t)o * HW_ + pg * 4] = v;
    }
}

// ---------------------------------------------------------------------------
// involution: out[b][g*16+cc][hw] = sum_k wk[b][g*9+k][hw] * x[b][g*16+cc][hw+off(k)]
// thread = (b, g, pixel); wk9 held in registers, reused over 16 channels
// ---------------------------------------------------------------------------
__global__ __launch_bounds__(256) void inv_kernel(const float* __restrict__ x,
                                                  const float* __restrict__ wk,
                                                  float* __restrict__ out) {
    const int tid = blockIdx.x * 256 + threadIdx.x;   // 0 .. B*G*HW-1
    const int hw  = tid & (HW_ - 1);
    const int g   = (tid >> 14) & (G_ - 1);
    const int b   = tid >> 18;
    const int h   = hw >> 7;
    const int w   = hw & (W_ - 1);

    float wk9[9];
    const float* wkp = wk + ((size_t)b * KO_ + g * 9) * HW_ + hw;
#pragma unroll
    for (int k = 0; k < 9; ++k) wk9[k] = wkp[(size_t)k * HW_];

    const float* xp = x + ((size_t)b * C_ + g * GC_) * HW_ + hw;
    float* op       = out + ((size_t)b * C_ + g * GC_) * HW_ + hw;

    const bool hok0 = (h > 0), hok2 = (h < H_ - 1);
    const bool wok0 = (w > 0), wok2 = (w < W_ - 1);

#pragma unroll 4
    for (int cc = 0; cc < GC_; ++cc) {
        const float* xc = xp + (size_t)cc * HW_;
        float acc = 0.f;
        if (hok0) {
            float xm = wok0 ? xc[-W_ - 1] : 0.f;
            float x0 = xc[-W_];
            float xq = wok2 ? xc[-W_ + 1] : 0.f;
            acc = fmaf(wk9[0], xm, acc);
            acc = fmaf(wk9[1], x0, acc);
            acc = fmaf(wk9[2], xq, acc);
        }
        {
            float xm = wok0 ? xc[-1] : 0.f;
            float x0 = xc[0];
            float xq = wok2 ? xc[1] : 0.f;
            acc = fmaf(wk9[3], xm, acc);
            acc = fmaf(wk9[4], x0, acc);
            acc = fmaf(wk9[5], xq, acc);
        }
        if (hok2) {
            float xm = wok0 ? xc[W_ - 1] : 0.f;
            float x0 = xc[W_];
            float xq = wok2 ? xc[W_ + 1] : 0.f;
            acc = fmaf(wk9[6], xm, acc);
            acc = fmaf(wk9[7], x0, acc);
            acc = fmaf(wk9[8], xq, acc);
        }
        op[(size_t)cc * HW_] = acc;
    }
}

// ---------------------------------------------------------------------------
extern "C" void kernel_launch(void* const* d_in, const int* in_sizes, int n_in,
                              void* d_out, int out_size, void* d_ws, size_t ws_size,
                              hipStream_t stream) {
    const float* x     = (const float*)d_in[0];
    const float* w1    = (const float*)d_in[1];
    const float* gamma = (const float*)d_in[2];
    const float* beta  = (const float*)d_in[3];
    const float* mean  = (const float*)d_in[4];
    const float* var   = (const float*)d_in[5];
    const float* w2    = (const float*)d_in[6];
    const float* b2    = (const float*)d_in[7];
    float* out = (float*)d_out;

    char* ws = (char*)d_ws;
    float* w1t   = (float*)(ws);                  // 64 KB  [256][64]
    float* bias2 = (float*)(ws + (64 << 10));     // 256 B
    float* w2t   = (float*)(ws + (128 << 10));    // 48 KB  [64][192]
    float* wkbuf = (float*)(ws + (1 << 20));      // 36 MB  [B][144][HW]

    hipLaunchKernelGGL(prep_kernel, dim3(64), dim3(256), 0, stream,
                       w1, gamma, beta, mean, var, w2, w1t, bias2, w2t);
    hipLaunchKernelGGL(conv12_kernel, dim3(1024), dim3(256), 0, stream,
                       x, w1t, bias2, w2t, b2, wkbuf);
    hipLaunchKernelGGL(inv_kernel, dim3(4096), dim3(256), 0, stream,
                       x, wkbuf, out);
}

// Round 5
// 77.675 us; speedup vs baseline: 2.1341x; 1.5072x over previous
//
#include <hip/hip_runtime.h>

#define B_   4
#define C_   256
#define CR_  64
#define H_   128
#define W_   128
#define HW_  (H_ * W_)
#define G_   16
#define GC_  16
#define KO_  144   // K*K*G = 9*16
#define EPS_ 1e-5f

typedef __bf16 bf16x8 __attribute__((ext_vector_type(8)));
typedef __bf16 bf16x2 __attribute__((ext_vector_type(2)));
typedef float  f32x4  __attribute__((ext_vector_type(4)));

#define SX 66   // LDS row stride (elements) for xs/hbuf: banks 2-way on gathers

// ---------------------------------------------------------------------------
// prep: build MFMA A-fragments (lane order: m = lane&15, kslot = 8*(lane>>4)+j;
// the kslot permutation cancels between A and B as long as both use it).
//  w1frag[kc][mt][lane][j] = bf16( w1[o=mt*16+(l&15)][c=kc*32+8*(l>>4)+j] * alpha[o] )
//  w2frag[mt][kc2][lane][j] = bf16( w2[o2=mt*16+(l&15)][cc=kc2*32+8*(l>>4)+j] )
//  bias2[o] = beta - mean*alpha
// ---------------------------------------------------------------------------
__global__ void prep_kernel(const float* __restrict__ w1,
                            const float* __restrict__ gamma,
                            const float* __restrict__ beta,
                            const float* __restrict__ mean,
                            const float* __restrict__ var,
                            const float* __restrict__ w2,
                            __bf16* __restrict__ w1frag,
                            __bf16* __restrict__ w2frag,
                            float* __restrict__ bias2) {
    int idx = blockIdx.x * 256 + threadIdx.x;
    if (idx < 16384) {                      // w1frag: [8 kc][4 mt][64 l][8 j]
        int kc = idx >> 11, r = idx & 2047;
        int mt = r >> 9, l = (r >> 3) & 63, j = r & 7;
        int o = mt * 16 + (l & 15);
        int c = kc * 32 + 8 * (l >> 4) + j;
        float alpha = gamma[o] * rsqrtf(var[o] + EPS_);
        w1frag[idx] = (__bf16)(w1[o * C_ + c] * alpha);
        if (idx < CR_) {
            float a2 = gamma[idx] * rsqrtf(var[idx] + EPS_);
            bias2[idx] = beta[idx] - mean[idx] * a2;
        }
    } else if (idx < 16384 + 9216) {        // w2frag: [9 mt][2 kc2][64 l][8 j]
        int i2 = idx - 16384;
        int mt = i2 >> 10, r = i2 & 1023;
        int kc2 = r >> 9, l = (r >> 3) & 63, j = r & 7;
        int o2 = mt * 16 + (l & 15);
        int cc = kc2 * 32 + 8 * (l >> 4) + j;
        w2frag[i2] = (__bf16)(w2[o2 * CR_ + cc]);
    }
}

// ---------------------------------------------------------------------------
// fused conv1(+BN+ReLU) + conv2 via bf16 MFMA, fp32 accumulate.
// Block = 64-pixel tile, 4 waves, grid 1024 (4 blocks/CU).
// Phase 1: h[64][64] : M=64(outs) x N=64(px) x K=256. Wave (wm,wn) owns
//   M-tiles {2wm,2wm+1} x N-tiles {2wn,2wn+1}; acc1[2][2] f32x4.
//   x staged per 32-K chunk into LDS bf16 [32][SX], double-buffered (T14).
// Phase 2: wk[144][64] : M=144 x N=64 x K=64. Wave owns N-tile=wave (16 px),
//   all 9 M-tiles; acc2[9] f32x4. B from hbuf (bf16 h in LDS).
// A-fragments read directly from global (L2-hot, pre-fragged by prep).
// D layout (verified): col(n)=lane&15, row(m)=4*(lane>>4)+reg.
// ---------------------------------------------------------------------------
__global__ __launch_bounds__(256, 4) void conv12_kernel(
        const float* __restrict__ x,
        const __bf16* __restrict__ w1frag,
        const float* __restrict__ bias2,
        const __bf16* __restrict__ w2frag,
        const float* __restrict__ b2,
        float* __restrict__ wk) {
    __shared__ __bf16 xs[2 * 32 * SX];     // 8.4 KB double-buffered x chunk
    __shared__ __bf16 hbuf[CR_ * SX];      // 8.4 KB h tile (bf16)

    const int tid  = threadIdx.x;
    const int lane = tid & 63;
    const int wave = tid >> 6;
    const int wm = wave >> 1, wn = wave & 1;
    const int g = lane >> 4, n = lane & 15;

    const int px0 = blockIdx.x * 64;
    const int b   = px0 >> 14;
    const int hw0 = px0 & (HW_ - 1);

    const float* xb = x + (size_t)b * C_ * HW_ + hw0;
    const int krow = tid >> 3;             // 0..31 (k row within chunk)
    const int t8   = tid & 7;              // 0..7  (two float4 segs per row)

    // ---- stage chunk 0 into buf 0 ----
    {
        float4 v0 = *(const float4*)&xb[(size_t)krow * HW_ + 4 * t8];
        float4 v1 = *(const float4*)&xb[(size_t)krow * HW_ + 32 + 4 * t8];
        __bf16* d0 = &xs[krow * SX + 4 * t8];
        __bf16* d1 = &xs[krow * SX + 32 + 4 * t8];
        *(bf16x2*)&d0[0] = bf16x2{(__bf16)v0.x, (__bf16)v0.y};
        *(bf16x2*)&d0[2] = bf16x2{(__bf16)v0.z, (__bf16)v0.w};
        *(bf16x2*)&d1[0] = bf16x2{(__bf16)v1.x, (__bf16)v1.y};
        *(bf16x2*)&d1[2] = bf16x2{(__bf16)v1.z, (__bf16)v1.w};
    }
    __syncthreads();

    // ======================= phase 1 ============================
    f32x4 acc1[2][2];
#pragma unroll
    for (int m = 0; m < 2; ++m)
#pragma unroll
        for (int t = 0; t < 2; ++t) acc1[m][t] = f32x4{0.f, 0.f, 0.f, 0.f};

    for (int kc = 0; kc < 8; ++kc) {
        const int buf = kc & 1;
        float4 nf0, nf1;
        if (kc < 7) {   // issue next chunk's loads early (hide HBM latency)
            nf0 = *(const float4*)&xb[(size_t)(32 * (kc + 1) + krow) * HW_ + 4 * t8];
            nf1 = *(const float4*)&xb[(size_t)(32 * (kc + 1) + krow) * HW_ + 32 + 4 * t8];
        }
        // A fragments (global, L2-hot, pre-fragged)
        bf16x8 a0 = *(const bf16x8*)&w1frag[((kc * 4 + 2 * wm + 0) * 64 + lane) * 8];
        bf16x8 a1 = *(const bf16x8*)&w1frag[((kc * 4 + 2 * wm + 1) * 64 + lane) * 8];
        // B fragments: gather bf16 from xs (kslot = 8g+j, matches A's layout)
        const int base = buf * (32 * SX);
        bf16x8 b0, b1;
#pragma unroll
        for (int j = 0; j < 8; ++j) {
            b0[j] = xs[base + (8 * g + j) * SX + (2 * wn + 0) * 16 + n];
            b1[j] = xs[base + (8 * g + j) * SX + (2 * wn + 1) * 16 + n];
        }
        acc1[0][0] = __builtin_amdgcn_mfma_f32_16x16x32_bf16(a0, b0, acc1[0][0], 0, 0, 0);
        acc1[0][1] = __builtin_amdgcn_mfma_f32_16x16x32_bf16(a0, b1, acc1[0][1], 0, 0, 0);
        acc1[1][0] = __builtin_amdgcn_mfma_f32_16x16x32_bf16(a1, b0, acc1[1][0], 0, 0, 0);
        acc1[1][1] = __builtin_amdgcn_mfma_f32_16x16x32_bf16(a1, b1, acc1[1][1], 0, 0, 0);

        if (kc < 7) {   // write next chunk into other buffer
            __bf16* d0 = &xs[(buf ^ 1) * (32 * SX) + krow * SX + 4 * t8];
            __bf16* d1 = &xs[(buf ^ 1) * (32 * SX) + krow * SX + 32 + 4 * t8];
            *(bf16x2*)&d0[0] = bf16x2{(__bf16)nf0.x, (__bf16)nf0.y};
            *(bf16x2*)&d0[2] = bf16x2{(__bf16)nf0.z, (__bf16)nf0.w};
            *(bf16x2*)&d1[0] = bf16x2{(__bf16)nf1.x, (__bf16)nf1.y};
            *(bf16x2*)&d1[2] = bf16x2{(__bf16)nf1.z, (__bf16)nf1.w};
        }
        __syncthreads();
    }

    // bias + relu -> hbuf (bf16). D elem: o = Mt*16+4g+j, px = Nt*16+n
#pragma unroll
    for (int m = 0; m < 2; ++m) {
        const int Mo = (2 * wm + m) * 16 + 4 * g;
        float4 bv = *(const float4*)&bias2[Mo];
        float bj[4] = {bv.x, bv.y, bv.z, bv.w};
#pragma unroll
        for (int t = 0; t < 2; ++t) {
            const int px = (2 * wn + t) * 16 + n;
#pragma unroll
            for (int j = 0; j < 4; ++j) {
                hbuf[(Mo + j) * SX + px] = (__bf16)fmaxf(acc1[m][t][j] + bj[j], 0.f);
            }
        }
    }
    __syncthreads();

    // ======================= phase 2 ============================
    f32x4 acc2[9];
#pragma unroll
    for (int m = 0; m < 9; ++m) acc2[m] = f32x4{0.f, 0.f, 0.f, 0.f};

#pragma unroll
    for (int kc2 = 0; kc2 < 2; ++kc2) {
        bf16x8 hb;
#pragma unroll
        for (int j = 0; j < 8; ++j)
            hb[j] = hbuf[(kc2 * 32 + 8 * g + j) * SX + wave * 16 + n];
#pragma unroll
        for (int mt = 0; mt < 9; ++mt) {
            bf16x8 a = *(const bf16x8*)&w2frag[((mt * 2 + kc2) * 64 + lane) * 8];
            acc2[mt] = __builtin_amdgcn_mfma_f32_16x16x32_bf16(a, hb, acc2[mt], 0, 0, 0);
        }
    }

    // store wk: o2 = mt*16+4g+j, px = wave*16+n
    float* wkb = wk + (size_t)b * KO_ * HW_ + hw0 + wave * 16 + n;
#pragma unroll
    for (int mt = 0; mt < 9; ++mt) {
        const int o0 = mt * 16 + 4 * g;
        float4 bv = *(const float4*)&b2[o0];
        float bj[4] = {bv.x, bv.y, bv.z, bv.w};
#pragma unroll
        for (int j = 0; j < 4; ++j)
            wkb[(size_t)(o0 + j) * HW_] = acc2[mt][j] + bj[j];
    }
}

// ---------------------------------------------------------------------------
// involution: out[b][g*16+cc][hw] = sum_k wk[b][g*9+k][hw] * x[b][g*16+cc][hw+off(k)]
// ---------------------------------------------------------------------------
__global__ __launch_bounds__(256) void inv_kernel(const float* __restrict__ x,
                                                  const float* __restrict__ wk,
                                                  float* __restrict__ out) {
    const int tid = blockIdx.x * 256 + threadIdx.x;   // 0 .. B*G*HW-1
    const int hw  = tid & (HW_ - 1);
    const int g   = (tid >> 14) & (G_ - 1);
    const int b   = tid >> 18;
    const int h   = hw >> 7;
    const int w   = hw & (W_ - 1);

    float wk9[9];
    const float* wkp = wk + ((size_t)b * KO_ + g * 9) * HW_ + hw;
#pragma unroll
    for (int k = 0; k < 9; ++k) wk9[k] = wkp[(size_t)k * HW_];

    const float* xp = x + ((size_t)b * C_ + g * GC_) * HW_ + hw;
    float* op       = out + ((size_t)b * C_ + g * GC_) * HW_ + hw;

    const bool hok0 = (h > 0), hok2 = (h < H_ - 1);
    const bool wok0 = (w > 0), wok2 = (w < W_ - 1);

#pragma unroll 4
    for (int cc = 0; cc < GC_; ++cc) {
        const float* xc = xp + (size_t)cc * HW_;
        float acc = 0.f;
        if (hok0) {
            float xm = wok0 ? xc[-W_ - 1] : 0.f;
            float x0 = xc[-W_];
            float xq = wok2 ? xc[-W_ + 1] : 0.f;
            acc = fmaf(wk9[0], xm, acc);
            acc = fmaf(wk9[1], x0, acc);
            acc = fmaf(wk9[2], xq, acc);
        }
        {
            float xm = wok0 ? xc[-1] : 0.f;
            float x0 = xc[0];
            float xq = wok2 ? xc[1] : 0.f;
            acc = fmaf(wk9[3], xm, acc);
            acc = fmaf(wk9[4], x0, acc);
            acc = fmaf(wk9[5], xq, acc);
        }
        if (hok2) {
            float xm = wok0 ? xc[W_ - 1] : 0.f;
            float x0 = xc[W_];
            float xq = wok2 ? xc[W_ + 1] : 0.f;
            acc = fmaf(wk9[6], xm, acc);
            acc = fmaf(wk9[7], x0, acc);
            acc = fmaf(wk9[8], xq, acc);
        }
        op[(size_t)cc * HW_] = acc;
    }
}

// ---------------------------------------------------------------------------
extern "C" void kernel_launch(void* const* d_in, const int* in_sizes, int n_in,
                              void* d_out, int out_size, void* d_ws, size_t ws_size,
                              hipStream_t stream) {
    const float* x     = (const float*)d_in[0];
    const float* w1    = (const float*)d_in[1];
    const float* gamma = (const float*)d_in[2];
    const float* beta  = (const float*)d_in[3];
    const float* mean  = (const float*)d_in[4];
    const float* var   = (const float*)d_in[5];
    const float* w2    = (const float*)d_in[6];
    const float* b2    = (const float*)d_in[7];
    float* out = (float*)d_out;

    char* ws = (char*)d_ws;
    __bf16* w1frag = (__bf16*)(ws);                 // 32 KB [8][4][64][8]
    __bf16* w2frag = (__bf16*)(ws + (32 << 10));    // 18 KB [9][2][64][8]
    float*  bias2  = (float*)(ws + (56 << 10));     // 256 B
    float*  wkbuf  = (float*)(ws + (1 << 20));      // 36 MB [B][144][HW]

    hipLaunchKernelGGL(prep_kernel, dim3(100), dim3(256), 0, stream,
                       w1, gamma, beta, mean, var, w2, w1frag, w2frag, bias2);
    hipLaunchKernelGGL(conv12_kernel, dim3(1024), dim3(256), 0, stream,
                       x, w1frag, bias2, w2frag, b2, wkbuf);
    hipLaunchKernelGGL(inv_kernel, dim3(4096), dim3(256), 0, stream,
                       x, wkbuf, out);
}

// Round 6
// 76.941 us; speedup vs baseline: 2.1545x; 1.0095x over previous
//
#include <hip/hip_runtime.h>

#define B_   4
#define C_   256
#define CR_  64
#define H_   128
#define W_   128
#define HW_  (H_ * W_)
#define G_   16
#define GC_  16
#define KO_  144   // K*K*G = 9*16
#define EPS_ 1e-5f

typedef __bf16 bf16x8 __attribute__((ext_vector_type(8)));
typedef __bf16 bf16x2 __attribute__((ext_vector_type(2)));
typedef float  f32x4  __attribute__((ext_vector_type(4)));

#define SX 66   // LDS row stride (elements) for xs/hbuf: banks 2-way on gathers

// ---------------------------------------------------------------------------
// prep: build MFMA A-fragments (lane order: m = lane&15, kslot = 8*(lane>>4)+j;
// the kslot permutation cancels between A and B as long as both use it).
//  w1frag[kc][mt][lane][j] = bf16( w1[o=mt*16+(l&15)][c=kc*32+8*(l>>4)+j] * alpha[o] )
//  w2frag[mt][kc2][lane][j] = bf16( w2[o2=mt*16+(l&15)][cc=kc2*32+8*(l>>4)+j] )
//  bias2[o] = beta - mean*alpha
// ---------------------------------------------------------------------------
__global__ void prep_kernel(const float* __restrict__ w1,
                            const float* __restrict__ gamma,
                            const float* __restrict__ beta,
                            const float* __restrict__ mean,
                            const float* __restrict__ var,
                            const float* __restrict__ w2,
                            __bf16* __restrict__ w1frag,
                            __bf16* __restrict__ w2frag,
                            float* __restrict__ bias2) {
    int idx = blockIdx.x * 256 + threadIdx.x;
    if (idx < 16384) {                      // w1frag: [8 kc][4 mt][64 l][8 j]
        int kc = idx >> 11, r = idx & 2047;
        int mt = r >> 9, l = (r >> 3) & 63, j = r & 7;
        int o = mt * 16 + (l & 15);
        int c = kc * 32 + 8 * (l >> 4) + j;
        float alpha = gamma[o] * rsqrtf(var[o] + EPS_);
        w1frag[idx] = (__bf16)(w1[o * C_ + c] * alpha);
        if (idx < CR_) {
            float a2 = gamma[idx] * rsqrtf(var[idx] + EPS_);
            bias2[idx] = beta[idx] - mean[idx] * a2;
        }
    } else if (idx < 16384 + 9216) {        // w2frag: [9 mt][2 kc2][64 l][8 j]
        int i2 = idx - 16384;
        int mt = i2 >> 10, r = i2 & 1023;
        int kc2 = r >> 9, l = (r >> 3) & 63, j = r & 7;
        int o2 = mt * 16 + (l & 15);
        int cc = kc2 * 32 + 8 * (l >> 4) + j;
        w2frag[i2] = (__bf16)(w2[o2 * CR_ + cc]);
    }
}

// ---------------------------------------------------------------------------
// fused conv1(+BN+ReLU) + conv2 via bf16 MFMA, fp32 accumulate.
// Block = 64-pixel tile, 4 waves, grid 1024 (4 blocks/CU).
// Phase 1: h[64][64] : M=64(outs) x N=64(px) x K=256. Wave (wm,wn) owns
//   M-tiles {2wm,2wm+1} x N-tiles {2wn,2wn+1}; acc1[2][2] f32x4.
//   x staged per 32-K chunk into LDS bf16 [32][SX], double-buffered (T14).
// Phase 2: wk[144][64] : M=144 x N=64 x K=64. Wave owns N-tile=wave (16 px),
//   all 9 M-tiles; acc2[9] f32x4. B from hbuf (bf16 h in LDS).
// A-fragments read directly from global (L2-hot, pre-fragged by prep).
// D layout (verified): col(n)=lane&15, row(m)=4*(lane>>4)+reg.
// ---------------------------------------------------------------------------
__global__ __launch_bounds__(256, 4) void conv12_kernel(
        const float* __restrict__ x,
        const __bf16* __restrict__ w1frag,
        const float* __restrict__ bias2,
        const __bf16* __restrict__ w2frag,
        const float* __restrict__ b2,
        float* __restrict__ wk) {
    __shared__ __bf16 xs[2 * 32 * SX];     // 8.4 KB double-buffered x chunk
    __shared__ __bf16 hbuf[CR_ * SX];      // 8.4 KB h tile (bf16)

    const int tid  = threadIdx.x;
    const int lane = tid & 63;
    const int wave = tid >> 6;
    const int wm = wave >> 1, wn = wave & 1;
    const int g = lane >> 4, n = lane & 15;

    const int px0 = blockIdx.x * 64;
    const int b   = px0 >> 14;
    const int hw0 = px0 & (HW_ - 1);

    const float* xb = x + (size_t)b * C_ * HW_ + hw0;
    const int krow = tid >> 3;             // 0..31 (k row within chunk)
    const int t8   = tid & 7;              // 0..7  (two float4 segs per row)

    // ---- stage chunk 0 into buf 0 ----
    {
        float4 v0 = *(const float4*)&xb[(size_t)krow * HW_ + 4 * t8];
        float4 v1 = *(const float4*)&xb[(size_t)krow * HW_ + 32 + 4 * t8];
        __bf16* d0 = &xs[krow * SX + 4 * t8];
        __bf16* d1 = &xs[krow * SX + 32 + 4 * t8];
        *(bf16x2*)&d0[0] = bf16x2{(__bf16)v0.x, (__bf16)v0.y};
        *(bf16x2*)&d0[2] = bf16x2{(__bf16)v0.z, (__bf16)v0.w};
        *(bf16x2*)&d1[0] = bf16x2{(__bf16)v1.x, (__bf16)v1.y};
        *(bf16x2*)&d1[2] = bf16x2{(__bf16)v1.z, (__bf16)v1.w};
    }
    __syncthreads();

    // ======================= phase 1 ============================
    f32x4 acc1[2][2];
#pragma unroll
    for (int m = 0; m < 2; ++m)
#pragma unroll
        for (int t = 0; t < 2; ++t) acc1[m][t] = f32x4{0.f, 0.f, 0.f, 0.f};

    for (int kc = 0; kc < 8; ++kc) {
        const int buf = kc & 1;
        float4 nf0, nf1;
        if (kc < 7) {   // issue next chunk's loads early (hide HBM latency)
            nf0 = *(const float4*)&xb[(size_t)(32 * (kc + 1) + krow) * HW_ + 4 * t8];
            nf1 = *(const float4*)&xb[(size_t)(32 * (kc + 1) + krow) * HW_ + 32 + 4 * t8];
        }
        // A fragments (global, L2-hot, pre-fragged)
        bf16x8 a0 = *(const bf16x8*)&w1frag[((kc * 4 + 2 * wm + 0) * 64 + lane) * 8];
        bf16x8 a1 = *(const bf16x8*)&w1frag[((kc * 4 + 2 * wm + 1) * 64 + lane) * 8];
        // B fragments: gather bf16 from xs (kslot = 8g+j, matches A's layout)
        const int base = buf * (32 * SX);
        bf16x8 b0, b1;
#pragma unroll
        for (int j = 0; j < 8; ++j) {
            b0[j] = xs[base + (8 * g + j) * SX + (2 * wn + 0) * 16 + n];
            b1[j] = xs[base + (8 * g + j) * SX + (2 * wn + 1) * 16 + n];
        }
        acc1[0][0] = __builtin_amdgcn_mfma_f32_16x16x32_bf16(a0, b0, acc1[0][0], 0, 0, 0);
        acc1[0][1] = __builtin_amdgcn_mfma_f32_16x16x32_bf16(a0, b1, acc1[0][1], 0, 0, 0);
        acc1[1][0] = __builtin_amdgcn_mfma_f32_16x16x32_bf16(a1, b0, acc1[1][0], 0, 0, 0);
        acc1[1][1] = __builtin_amdgcn_mfma_f32_16x16x32_bf16(a1, b1, acc1[1][1], 0, 0, 0);

        if (kc < 7) {   // write next chunk into other buffer
            __bf16* d0 = &xs[(buf ^ 1) * (32 * SX) + krow * SX + 4 * t8];
            __bf16* d1 = &xs[(buf ^ 1) * (32 * SX) + krow * SX + 32 + 4 * t8];
            *(bf16x2*)&d0[0] = bf16x2{(__bf16)nf0.x, (__bf16)nf0.y};
            *(bf16x2*)&d0[2] = bf16x2{(__bf16)nf0.z, (__bf16)nf0.w};
            *(bf16x2*)&d1[0] = bf16x2{(__bf16)nf1.x, (__bf16)nf1.y};
            *(bf16x2*)&d1[2] = bf16x2{(__bf16)nf1.z, (__bf16)nf1.w};
        }
        __syncthreads();
    }

    // bias + relu -> hbuf (bf16). D elem: o = Mt*16+4g+j, px = Nt*16+n
#pragma unroll
    for (int m = 0; m < 2; ++m) {
        const int Mo = (2 * wm + m) * 16 + 4 * g;
        float4 bv = *(const float4*)&bias2[Mo];
        float bj[4] = {bv.x, bv.y, bv.z, bv.w};
#pragma unroll
        for (int t = 0; t < 2; ++t) {
            const int px = (2 * wn + t) * 16 + n;
#pragma unroll
            for (int j = 0; j < 4; ++j) {
                hbuf[(Mo + j) * SX + px] = (__bf16)fmaxf(acc1[m][t][j] + bj[j], 0.f);
            }
        }
    }
    __syncthreads();

    // ======================= phase 2 ============================
    f32x4 acc2[9];
#pragma unroll
    for (int m = 0; m < 9; ++m) acc2[m] = f32x4{0.f, 0.f, 0.f, 0.f};

#pragma unroll
    for (int kc2 = 0; kc2 < 2; ++kc2) {
        bf16x8 hb;
#pragma unroll
        for (int j = 0; j < 8; ++j)
            hb[j] = hbuf[(kc2 * 32 + 8 * g + j) * SX + wave * 16 + n];
#pragma unroll
        for (int mt = 0; mt < 9; ++mt) {
            bf16x8 a = *(const bf16x8*)&w2frag[((mt * 2 + kc2) * 64 + lane) * 8];
            acc2[mt] = __builtin_amdgcn_mfma_f32_16x16x32_bf16(a, hb, acc2[mt], 0, 0, 0);
        }
    }

    // store wk: o2 = mt*16+4g+j, px = wave*16+n
    float* wkb = wk + (size_t)b * KO_ * HW_ + hw0 + wave * 16 + n;
#pragma unroll
    for (int mt = 0; mt < 9; ++mt) {
        const int o0 = mt * 16 + 4 * g;
        float4 bv = *(const float4*)&b2[o0];
        float bj[4] = {bv.x, bv.y, bv.z, bv.w};
#pragma unroll
        for (int j = 0; j < 4; ++j)
            wkb[(size_t)(o0 + j) * HW_] = acc2[mt][j] + bj[j];
    }
}

// ---------------------------------------------------------------------------
// involution: out[b][g*16+cc][hw] = sum_k wk[b][g*9+k][hw] * x[b][g*16+cc][hw+off(k)]
// ---------------------------------------------------------------------------
__global__ __launch_bounds__(256) void inv_kernel(const float* __restrict__ x,
                                                  const float* __restrict__ wk,
                                                  float* __restrict__ out) {
    const int tid = blockIdx.x * 256 + threadIdx.x;   // 0 .. B*G*HW-1
    const int hw  = tid & (HW_ - 1);
    const int g   = (tid >> 14) & (G_ - 1);
    const int b   = tid >> 18;
    const int h   = hw >> 7;
    const int w   = hw & (W_ - 1);

    float wk9[9];
    const float* wkp = wk + ((size_t)b * KO_ + g * 9) * HW_ + hw;
#pragma unroll
    for (int k = 0; k < 9; ++k) wk9[k] = wkp[(size_t)k * HW_];

    const float* xp = x + ((size_t)b * C_ + g * GC_) * HW_ + hw;
    float* op       = out + ((size_t)b * C_ + g * GC_) * HW_ + hw;

    const bool hok0 = (h > 0), hok2 = (h < H_ - 1);
    const bool wok0 = (w > 0), wok2 = (w < W_ - 1);

#pragma unroll 4
    for (int cc = 0; cc < GC_; ++cc) {
        const float* xc = xp + (size_t)cc * HW_;
        float acc = 0.f;
        if (hok0) {
            float xm = wok0 ? xc[-W_ - 1] : 0.f;
            float x0 = xc[-W_];
            float xq = wok2 ? xc[-W_ + 1] : 0.f;
            acc = fmaf(wk9[0], xm, acc);
            acc = fmaf(wk9[1], x0, acc);
            acc = fmaf(wk9[2], xq, acc);
        }
        {
            float xm = wok0 ? xc[-1] : 0.f;
            float x0 = xc[0];
            float xq = wok2 ? xc[1] : 0.f;
            acc = fmaf(wk9[3], xm, acc);
            acc = fmaf(wk9[4], x0, acc);
            acc = fmaf(wk9[5], xq, acc);
        }
        if (hok2) {
            float xm = wok0 ? xc[W_ - 1] : 0.f;
            float x0 = xc[W_];
            float xq = wok2 ? xc[W_ + 1] : 0.f;
            acc = fmaf(wk9[6], xm, acc);
            acc = fmaf(wk9[7], x0, acc);
            acc = fmaf(wk9[8], xq, acc);
        }
        op[(size_t)cc * HW_] = acc;
    }
}

// ---------------------------------------------------------------------------
extern "C" void kernel_launch(void* const* d_in, const int* in_sizes, int n_in,
                              void* d_out, int out_size, void* d_ws, size_t ws_size,
                              hipStream_t stream) {
    const float* x     = (const float*)d_in[0];
    const float* w1    = (const float*)d_in[1];
    const float* gamma = (const float*)d_in[2];
    const float* beta  = (const float*)d_in[3];
    const float* mean  = (const float*)d_in[4];
    const float* var   = (const float*)d_in[5];
    const float* w2    = (const float*)d_in[6];
    const float* b2    = (const float*)d_in[7];
    float* out = (float*)d_out;

    char* ws = (char*)d_ws;
    __bf16* w1frag = (__bf16*)(ws);                 // 32 KB [8][4][64][8]
    __bf16* w2frag = (__bf16*)(ws + (32 << 10));    // 18 KB [9][2][64][8]
    float*  bias2  = (float*)(ws + (56 << 10));     // 256 B
    float*  wkbuf  = (float*)(ws + (1 << 20));      // 36 MB [B][144][HW]

    hipLaunchKernelGGL(prep_kernel, dim3(100), dim3(256), 0, stream,
                       w1, gamma, beta, mean, var, w2, w1frag, w2frag, bias2);
    hipLaunchKernelGGL(conv12_kernel, dim3(1024), dim3(256), 0, stream,
                       x, w1frag, bias2, w2frag, b2, wkbuf);
    hipLaunchKernelGGL(inv_kernel, dim3(4096), dim3(256), 0, stream,
                       x, wkbuf, out);
}